// Round 3
// baseline (225.658 us; speedup 1.0000x reference)
//
#include <hip/hip_runtime.h>

#define NS 8192
#define EMBED 128
#define COLCHUNK 1024            // grid.y = 8 chunks of 1024 cols
#define PHROW 12                 // pos-hist row stride (11 bins + 1 pad)

typedef __bf16 bf16x8 __attribute__((ext_vector_type(8)));
typedef float f32x4 __attribute__((ext_vector_type(4)));

// workspace layout (bytes from ws start)
#define OFF_XB 0u                        // bf16 [8192][128] = 2 MiB
#define OFF_GS (2097152u)                // fp32 [8192][12]  = 384 KiB (S sums)
#define OFF_GP (2097152u + 393216u)      // u32  [8192][12]  = 384 KiB (pos hist)
#define OFF_CC (2097152u + 786432u)      // int  [128] class counts
#define OFF_AC (2097152u + 786944u)      // float[2] accum + u32 done
#define ZERO_BYTES (786976u)             // gS..done zero range (16B multiple)

__device__ inline unsigned short f2bf(float f) {
  unsigned u = __float_as_uint(f);
  u += 0x7fffu + ((u >> 16) & 1u);   // round-to-nearest-even
  return (unsigned short)(u >> 16);
}

// ---- prep: fp32->bf16 convert + zero all accumulator regions ----
__global__ __launch_bounds__(256) void prep_kernel(const float* __restrict__ x,
                                                   unsigned short* __restrict__ xb,
                                                   uint4* __restrict__ zbase) {
  const int gid = blockIdx.x * 256 + threadIdx.x;   // grid exactly covers 8192*128/4
  float4 v = reinterpret_cast<const float4*>(x)[gid];
  ushort4 o;
  o.x = f2bf(v.x); o.y = f2bf(v.y); o.z = f2bf(v.z); o.w = f2bf(v.w);
  reinterpret_cast<ushort4*>(xb)[gid] = o;
  if (gid < (int)(ZERO_BYTES / 16u)) zbase[gid] = make_uint4(0u, 0u, 0u, 0u);
}

// ---- main: dist2 MFMA + branchless register soft-histogram ----
// Block = 256 thr (4 waves), 64 rows/block, grid.y splits cols into 8 chunks.
// Negative+positive combined hist accumulated as S[k] = sum min(|t-k|,1) in
// REGISTERS (no atomics, no bank conflicts); h_all[k] = 8192 - S_total[k].
// Diagonal excluded via t=1e9 sentinel (contributes exactly 1 to every S[k]).
// Rare positives (~1%) scattered into small LDS hist under an exec-masked branch.
__global__ __launch_bounds__(256, 4) void fastap_main_kernel(
    const unsigned short* __restrict__ xb,
    const int* __restrict__ labels,
    float* __restrict__ gS,
    unsigned* __restrict__ gP,
    int* __restrict__ ccount) {
  __shared__ int sLab[COLCHUNK];
  __shared__ unsigned sHp[64 * PHROW];

  const int tid  = threadIdx.x;
  const int wave = tid >> 6;
  const int lane = tid & 63;
  const int l16  = lane & 15;
  const int quad = lane >> 4;
  const int rowBase  = blockIdx.x * 64;
  const int colBegin = blockIdx.y * COLCHUNK;
  const int rl0 = wave * 16 + quad * 4;   // first of this lane's 4 rows

  // class counts (once: only y==0 blocks, each counts its own 64 rows)
  if (blockIdx.y == 0 && tid < 64) atomicAdd(&ccount[labels[rowBase + tid]], 1);

  // stage this chunk's labels (1024 ints = 256 x int4)
  reinterpret_cast<int4*>(sLab)[tid] =
      reinterpret_cast<const int4*>(labels + colBegin)[tid];
  for (int idx = tid; idx < 64 * PHROW; idx += 256) sHp[idx] = 0u;

  // A fragments: this wave's 16 rows, K=128, in registers for the whole sweep.
  bf16x8 afr[4];
  const int arow = rowBase + wave * 16 + l16;
  #pragma unroll
  for (int kb = 0; kb < 4; ++kb)
    afr[kb] = *reinterpret_cast<const bf16x8*>(&xb[arow * EMBED + kb * 32 + quad * 8]);

  int labi[4];
  #pragma unroll
  for (int r = 0; r < 4; ++r) labi[r] = labels[rowBase + rl0 + r];

  float S[4][11];
  #pragma unroll
  for (int r = 0; r < 4; ++r)
    #pragma unroll
    for (int k = 0; k < 11; ++k) S[r][k] = 0.f;

  __syncthreads();

  for (int c0 = 0; c0 < COLCHUNK; c0 += 16) {
    const int ct = colBegin + c0;
    // B fragments straight from global (L2-resident; same layout as A side)
    bf16x8 bfr[4];
    #pragma unroll
    for (int kb = 0; kb < 4; ++kb)
      bfr[kb] = *reinterpret_cast<const bf16x8*>(
          &xb[(ct + l16) * EMBED + kb * 32 + quad * 8]);

    f32x4 acc = {0.f, 0.f, 0.f, 0.f};
    #pragma unroll
    for (int kb = 0; kb < 4; ++kb)
      acc = __builtin_amdgcn_mfma_f32_16x16x32_bf16(afr[kb], bfr[kb], acc, 0, 0, 0);

    const int j    = ct + l16;           // C/D: col = lane&15
    const int labj = sLab[c0 + l16];

    #pragma unroll
    for (int r = 0; r < 4; ++r) {        // C/D: row = quad*4 + reg
      float t = fmaf(acc[r], -5.f, 5.f); // t = (2-2c)/0.4 = 5 - 5c
      t = (rowBase + rl0 + r == j) ? 1.0e9f : t;   // diagonal sentinel

      if (labi[r] == labj) {             // rare positive: exact 2-bin scatter
        const float kf = floorf(t);
        const int   k  = (int)kf;
        const unsigned w2q = (unsigned)((t - kf) * 65536.f + 0.5f);
        const unsigned w1q = 65536u - w2q;
        unsigned* hr = &sHp[(rl0 + r) * PHROW];
        if (k >= 0 && k <= 10) atomicAdd(hr + k, w1q);
        if (k >= -1 && k <= 9) atomicAdd(hr + k + 1, w2q);
      }

      #pragma unroll
      for (int k = 0; k < 11; ++k)       // 3 VALU/bin, fixed regs, no atomics
        S[r][k] += fminf(fabsf(t - (float)k), 1.0f);
    }
  }

  // reduce S across the 16 lanes sharing each row (butterfly, once per block)
  #pragma unroll
  for (int m = 1; m < 16; m <<= 1)
    #pragma unroll
    for (int r = 0; r < 4; ++r)
      #pragma unroll
      for (int k = 0; k < 11; ++k)
        S[r][k] += __shfl_xor(S[r][k], m, 64);

  if (l16 == 0) {
    #pragma unroll
    for (int r = 0; r < 4; ++r)
      #pragma unroll
      for (int k = 0; k < 11; ++k)
        atomicAdd(&gS[(rowBase + rl0 + r) * PHROW + k], S[r][k]);
  }

  __syncthreads();
  for (int idx = tid; idx < 64 * PHROW; idx += 256) {
    const unsigned v = sHp[idx];
    if (v) atomicAdd(&gP[rowBase * PHROW + idx], v);
  }
}

// ---- epilogue: per-row AP + final loss (last block finalizes) ----
__global__ __launch_bounds__(256) void epilogue_kernel(
    const float* __restrict__ gS, const unsigned* __restrict__ gP,
    const int* __restrict__ labels, const int* __restrict__ ccount,
    float* __restrict__ accum, unsigned* __restrict__ done,
    float* __restrict__ out) {
  const int i = blockIdx.x * 256 + threadIdx.x;
  float Hs = 0.f, Hp = 0.f, ap = 0.f, val = 0.f;
  #pragma unroll
  for (int l = 0; l < 11; ++l) {
    const float hall = 8192.f - gS[i * PHROW + l];        // pos+neg, diag excluded
    const float hp   = (float)gP[i * PHROW + l] * (1.f / 65536.f);
    Hp += hp;
    Hs += hall;
    if (Hs > 0.f) ap += hp * Hp / Hs;
  }
  const int np = ccount[labels[i]] - 1;    // N_pos = classCount - 1
  if (np > 0) { ap /= (float)np; val = 1.f; } else ap = 0.f;

  __shared__ float sa[256], sv[256];
  sa[threadIdx.x] = ap; sv[threadIdx.x] = val;
  __syncthreads();
  for (int s = 128; s > 0; s >>= 1) {
    if (threadIdx.x < s) {
      sa[threadIdx.x] += sa[threadIdx.x + s];
      sv[threadIdx.x] += sv[threadIdx.x + s];
    }
    __syncthreads();
  }
  if (threadIdx.x == 0) {
    atomicAdd(&accum[0], sa[0]);
    atomicAdd(&accum[1], sv[0]);
    __threadfence();
    const unsigned prev = atomicAdd(done, 1u);
    if (prev == gridDim.x - 1) {
      const float a = atomicAdd(&accum[0], 0.f);   // coherent reads
      const float c = atomicAdd(&accum[1], 0.f);
      out[0] = 1.f - (c > 0.f ? a / c : 0.f);
    }
  }
}

extern "C" void kernel_launch(void* const* d_in, const int* in_sizes, int n_in,
                              void* d_out, int out_size, void* d_ws, size_t ws_size,
                              hipStream_t stream) {
  const float* x      = (const float*)d_in[0];
  const int*   labels = (const int*)d_in[1];
  float* out = (float*)d_out;

  char* ws = (char*)d_ws;
  unsigned short* xb = (unsigned short*)(ws + OFF_XB);
  float*    gS       = (float*)(ws + OFF_GS);
  unsigned* gP       = (unsigned*)(ws + OFF_GP);
  int*      ccount   = (int*)(ws + OFF_CC);
  float*    accum    = (float*)(ws + OFF_AC);
  unsigned* done     = (unsigned*)(ws + OFF_AC + 8);

  prep_kernel<<<(NS * EMBED / 4) / 256, 256, 0, stream>>>(x, xb, (uint4*)(ws + OFF_GS));
  fastap_main_kernel<<<dim3(NS / 64, NS / COLCHUNK), 256, 0, stream>>>(
      xb, labels, gS, gP, ccount);
  epilogue_kernel<<<NS / 256, 256, 0, stream>>>(gS, gP, labels, ccount, accum, done, out);
}

// Round 4
// 214.908 us; speedup vs baseline: 1.0500x; 1.0500x over previous
//
#include <hip/hip_runtime.h>

#define NS 8192
#define EMBED 128
#define COLCHUNK 1024            // grid.y = 8 chunks of 1024 cols
#define AROW 12                  // adj-hist row stride (11 bins + 1 pad)
#define INV64K (1.0f / 65536.0f)

typedef __bf16 bf16x8 __attribute__((ext_vector_type(8)));
typedef float f32x4 __attribute__((ext_vector_type(4)));

// workspace layout (bytes from ws start)
#define OFF_XB  0u               // bf16 [8192][128] = 2 MiB
#define OFF_GS  2097152u         // fp32 [8192][4]   cumulative C bins 3..6
#define OFF_GSP 2228224u         // fp32 [8192][4]   cumulative Cp bins 3..6
#define OFF_GA  2359296u         // i32  [8192][12]  all-hist corrections (q16)
#define OFF_GAP 2752512u         // i32  [8192][12]  pos-hist corrections (q16)
#define OFF_CC  3145728u         // int  [128] class counts
#define OFF_AC  3146240u         // float[2] accum + u32 done
#define ZERO_BYTES 1049120u      // OFF_GS .. end (16B multiple)

__device__ inline unsigned short f2bf(float f) {
  unsigned u = __float_as_uint(f);
  u += 0x7fffu + ((u >> 16) & 1u);   // round-to-nearest-even
  return (unsigned short)(u >> 16);
}
__device__ inline float clamp01(float x) { return fminf(fmaxf(x, 0.f), 1.f); }

// ---- prep: fp32->bf16 convert + zero all accumulator regions ----
__global__ __launch_bounds__(256) void prep_kernel(const float* __restrict__ x,
                                                   unsigned short* __restrict__ xb,
                                                   uint4* __restrict__ zbase) {
  const int gid = blockIdx.x * 256 + threadIdx.x;   // grid covers 8192*128/4
  float4 v = reinterpret_cast<const float4*>(x)[gid];
  ushort4 o;
  o.x = f2bf(v.x); o.y = f2bf(v.y); o.z = f2bf(v.z); o.w = f2bf(v.w);
  reinterpret_cast<ushort4*>(xb)[gid] = o;
  if (gid < (int)(ZERO_BYTES / 16u)) zbase[gid] = make_uint4(0u, 0u, 0u, 0u);
}

// ---- main: dist2 MFMA + 4-bin cumulative register histogram ----
// t = dist2/Delta = 5 - 5*cos.  Cumulative hist H[k] = sum clamp(k+1-t,0,1).
// Registers keep ONLY bins 3..6 (exact formula clamp((k-4)-u,0,1), u=-5cos,
// constants -1,0,1,2 all inline).  Bins >=7: base count (8192 resp. Npos);
// bins <=2: base 0.  Rare lanes (|u|>2, incl. the diagonal where u~=-5) fix
// everything up via signed q16 atomics into small LDS adj-hists.
// Positives are branchless: Cp[k] += pm * d[k].
__global__ __launch_bounds__(256, 4) void fastap_main_kernel(
    const unsigned short* __restrict__ xb,
    const int* __restrict__ labels,
    float* __restrict__ gS, float* __restrict__ gSp,
    unsigned* __restrict__ gA, unsigned* __restrict__ gAp,
    int* __restrict__ ccount) {
  __shared__ int sLab[COLCHUNK];
  __shared__ unsigned sHs[64 * AROW];   // all-hist corrections (signed q16)
  __shared__ unsigned sHsp[64 * AROW];  // pos-hist corrections (signed q16)

  const int tid  = threadIdx.x;
  const int wave = tid >> 6;
  const int lane = tid & 63;
  const int l16  = lane & 15;
  const int quad = lane >> 4;
  const int rowBase  = blockIdx.x * 64;
  const int colBegin = blockIdx.y * COLCHUNK;
  const int rl0 = wave * 16 + quad * 4;   // first of this lane's 4 rows

  if (blockIdx.y == 0 && tid < 64) atomicAdd(&ccount[labels[rowBase + tid]], 1);

  reinterpret_cast<int4*>(sLab)[tid] =
      reinterpret_cast<const int4*>(labels + colBegin)[tid];
  for (int idx = tid; idx < 64 * AROW; idx += 256) { sHs[idx] = 0u; sHsp[idx] = 0u; }

  bf16x8 afr[4];
  const int arow = rowBase + wave * 16 + l16;
  #pragma unroll
  for (int kb = 0; kb < 4; ++kb)
    afr[kb] = *reinterpret_cast<const bf16x8*>(&xb[arow * EMBED + kb * 32 + quad * 8]);

  int labi[4], iRow[4];
  #pragma unroll
  for (int r = 0; r < 4; ++r) {
    iRow[r] = rowBase + rl0 + r;
    labi[r] = labels[iRow[r]];
  }

  float C[4][4], Cp[4][4];
  #pragma unroll
  for (int r = 0; r < 4; ++r)
    #pragma unroll
    for (int k = 0; k < 4; ++k) { C[r][k] = 0.f; Cp[r][k] = 0.f; }

  __syncthreads();

  for (int c0 = 0; c0 < COLCHUNK; c0 += 16) {
    const int ct = colBegin + c0;
    bf16x8 bfr[4];
    #pragma unroll
    for (int kb = 0; kb < 4; ++kb)
      bfr[kb] = *reinterpret_cast<const bf16x8*>(
          &xb[(ct + l16) * EMBED + kb * 32 + quad * 8]);

    // two independent 2-chains halve the MFMA dependency latency
    f32x4 acc0 = {0.f, 0.f, 0.f, 0.f}, acc1 = {0.f, 0.f, 0.f, 0.f};
    acc0 = __builtin_amdgcn_mfma_f32_16x16x32_bf16(afr[0], bfr[0], acc0, 0, 0, 0);
    acc0 = __builtin_amdgcn_mfma_f32_16x16x32_bf16(afr[1], bfr[1], acc0, 0, 0, 0);
    acc1 = __builtin_amdgcn_mfma_f32_16x16x32_bf16(afr[2], bfr[2], acc1, 0, 0, 0);
    acc1 = __builtin_amdgcn_mfma_f32_16x16x32_bf16(afr[3], bfr[3], acc1, 0, 0, 0);

    const int j    = ct + l16;           // C/D: col = lane&15
    const int labj = sLab[c0 + l16];

    #pragma unroll
    for (int r = 0; r < 4; ++r) {        // C/D: row = quad*4 + reg
      const float u = -5.f * (acc0[r] + acc1[r]);     // u = t - 5
      const bool isPos = (labi[r] == labj) & (iRow[r] != j);
      const float pm = isPos ? 1.f : 0.f;
      const float d0 = clamp01(-1.f - u);   // bin 3
      const float d1 = clamp01( 0.f - u);   // bin 4
      const float d2 = clamp01( 1.f - u);   // bin 5
      const float d3 = clamp01( 2.f - u);   // bin 6
      C[r][0] += d0; C[r][1] += d1; C[r][2] += d2; C[r][3] += d3;
      Cp[r][0] = fmaf(pm, d0, Cp[r][0]);
      Cp[r][1] = fmaf(pm, d1, Cp[r][1]);
      Cp[r][2] = fmaf(pm, d2, Cp[r][2]);
      Cp[r][3] = fmaf(pm, d3, Cp[r][3]);

      if (fabsf(u) > 2.f) {              // rare: outlier or diagonal
        const int row = rl0 + r;
        if (iRow[r] == j) {
          // diagonal: cancel fast contributions and the bins>=7 base (+1)
          C[r][0] -= d0; C[r][1] -= d1; C[r][2] -= d2; C[r][3] -= d3;
          #pragma unroll
          for (int k = 7; k <= 10; ++k)
            atomicAdd(&sHs[row * AROW + k], (unsigned)(-65536));
        } else {
          const float t = u + 5.f;
          #pragma unroll
          for (int k = 0; k <= 2; ++k) {   // assumed 0
            const float v = clamp01((float)(k + 1) - t);
            const int q = (int)(v * 65536.f + 0.5f);
            if (q) {
              atomicAdd(&sHs[row * AROW + k], (unsigned)q);
              if (isPos) atomicAdd(&sHsp[row * AROW + k], (unsigned)q);
            }
          }
          #pragma unroll
          for (int k = 7; k <= 10; ++k) {  // assumed 1
            const float v = clamp01((float)(k + 1) - t) - 1.f;
            const int q = (int)(v * 65536.f - 0.5f);
            if (q) {
              atomicAdd(&sHs[row * AROW + k], (unsigned)q);
              if (isPos) atomicAdd(&sHsp[row * AROW + k], (unsigned)q);
            }
          }
        }
      }
    }
  }

  // butterfly-reduce C/Cp across the 16 lanes sharing each row
  #pragma unroll
  for (int m = 1; m < 16; m <<= 1)
    #pragma unroll
    for (int r = 0; r < 4; ++r)
      #pragma unroll
      for (int k = 0; k < 4; ++k) {
        C[r][k]  += __shfl_xor(C[r][k],  m, 64);
        Cp[r][k] += __shfl_xor(Cp[r][k], m, 64);
      }

  if (l16 == 0) {
    #pragma unroll
    for (int r = 0; r < 4; ++r)
      #pragma unroll
      for (int k = 0; k < 4; ++k) {
        atomicAdd(&gS[(rowBase + rl0 + r) * 4 + k],  C[r][k]);
        atomicAdd(&gSp[(rowBase + rl0 + r) * 4 + k], Cp[r][k]);
      }
  }

  __syncthreads();
  for (int idx = tid; idx < 64 * AROW; idx += 256) {
    const unsigned v = sHs[idx], vp = sHsp[idx];
    if (v)  atomicAdd(&gA[rowBase * AROW + idx], v);
    if (vp) atomicAdd(&gAp[rowBase * AROW + idx], vp);
  }
}

// ---- epilogue: per-row AP + final loss (last block finalizes) ----
__global__ __launch_bounds__(256) void epilogue_kernel(
    const float* __restrict__ gS, const float* __restrict__ gSp,
    const unsigned* __restrict__ gA, const unsigned* __restrict__ gAp,
    const int* __restrict__ labels, const int* __restrict__ ccount,
    float* __restrict__ accum, unsigned* __restrict__ done,
    float* __restrict__ out) {
  const int i = blockIdx.x * 256 + threadIdx.x;
  const int np = ccount[labels[i]] - 1;   // N_pos = classCount - 1
  float ap = 0.f, val = 0.f, HpPrev = 0.f;
  #pragma unroll
  for (int b = 0; b <= 10; ++b) {
    const float baseH  = (b < 3) ? 0.f : (b < 7) ? gS[i * 4 + (b - 3)]  : 8192.f;
    const float basePp = (b < 3) ? 0.f : (b < 7) ? gSp[i * 4 + (b - 3)] : (float)np;
    const float H  = baseH  + (float)(int)gA[i * AROW + b]  * INV64K;
    const float Hp = basePp + (float)(int)gAp[i * AROW + b] * INV64K;
    const float hp = Hp - HpPrev;
    HpPrev = Hp;
    if (H > 1e-6f) ap += hp * Hp / H;
  }
  if (np > 0) { ap /= (float)np; val = 1.f; } else ap = 0.f;

  __shared__ float sa[256], sv[256];
  sa[threadIdx.x] = ap; sv[threadIdx.x] = val;
  __syncthreads();
  for (int s = 128; s > 0; s >>= 1) {
    if (threadIdx.x < s) {
      sa[threadIdx.x] += sa[threadIdx.x + s];
      sv[threadIdx.x] += sv[threadIdx.x + s];
    }
    __syncthreads();
  }
  if (threadIdx.x == 0) {
    atomicAdd(&accum[0], sa[0]);
    atomicAdd(&accum[1], sv[0]);
    __threadfence();
    const unsigned prev = atomicAdd(done, 1u);
    if (prev == gridDim.x - 1) {
      const float a = atomicAdd(&accum[0], 0.f);   // coherent reads
      const float c = atomicAdd(&accum[1], 0.f);
      out[0] = 1.f - (c > 0.f ? a / c : 0.f);
    }
  }
}

extern "C" void kernel_launch(void* const* d_in, const int* in_sizes, int n_in,
                              void* d_out, int out_size, void* d_ws, size_t ws_size,
                              hipStream_t stream) {
  const float* x      = (const float*)d_in[0];
  const int*   labels = (const int*)d_in[1];
  float* out = (float*)d_out;

  char* ws = (char*)d_ws;
  unsigned short* xb = (unsigned short*)(ws + OFF_XB);
  float*    gS   = (float*)(ws + OFF_GS);
  float*    gSp  = (float*)(ws + OFF_GSP);
  unsigned* gA   = (unsigned*)(ws + OFF_GA);
  unsigned* gAp  = (unsigned*)(ws + OFF_GAP);
  int*      cc   = (int*)(ws + OFF_CC);
  float*    accum = (float*)(ws + OFF_AC);
  unsigned* done  = (unsigned*)(ws + OFF_AC + 8);

  prep_kernel<<<(NS * EMBED / 4) / 256, 256, 0, stream>>>(x, xb, (uint4*)(ws + OFF_GS));
  fastap_main_kernel<<<dim3(NS / 64, NS / COLCHUNK), 256, 0, stream>>>(
      xb, labels, gS, gSp, gA, gAp, cc);
  epilogue_kernel<<<NS / 256, 256, 0, stream>>>(gS, gSp, gA, gAp, labels, cc,
                                                accum, done, out);
}